// Round 1
// baseline (1058.538 us; speedup 1.0000x reference)
//
#include <hip/hip_runtime.h>
#include <math.h>

#define DD 256
#define BB 1024
#define CC 64
#define VV 50000
#define TOPK 10
#define NT 128
#define MT 64
#define KT 16
#define NCHUNK 391   // ceil(VV/NT)

// ---------------- Kernel 1: gather + attention + phrase ----------------
__global__ __launch_bounds__(256) void k_phrase(
    const int* __restrict__ wl_ids, const int* __restrict__ wr_ids,
    const int* __restrict__ cl_ids, const int* __restrict__ cr_ids,
    const float* __restrict__ WE, const float* __restrict__ CE,
    const float* __restrict__ W_a, const float* __restrict__ b_a,
    const float* __restrict__ W_c, const float* __restrict__ b_c,
    float* __restrict__ phrase)
{
    const int b = blockIdx.x;
    const int t = threadIdx.x;
    __shared__ float s_wl[DD], s_wr[DD], s_align[DD], s_agg0[DD], s_agg1[DD];
    __shared__ float s_part[256];
    __shared__ float s_att[CC];
    __shared__ int s_rid[CC];

    s_wl[t] = WE[(size_t)wl_ids[b] * DD + t];
    s_wr[t] = WE[(size_t)wr_ids[b] * DD + t];
    __syncthreads();

    for (int side = 0; side < 2; ++side) {
        // side 0: word=wl attends over RIGHT candidates (aggre_l)
        // side 1: word=wr attends over LEFT candidates (aggre_r)
        const float* w    = (side == 0) ? s_wl : s_wr;
        const int*   cids = (side == 0) ? (cr_ids + b * CC) : (cl_ids + b * CC);

        float acc = b_a[t];
        #pragma unroll 4
        for (int k = 0; k < DD; ++k) acc = fmaf(w[k], W_a[k * DD + t], acc);
        s_align[t] = tanhf(acc);
        if (t < CC) s_rid[t] = cids[t];
        __syncthreads();

        {   // scores: 4 partial sums per candidate
            const int c = t & 63, p = t >> 6;
            const float* crow = CE + (size_t)s_rid[c] * DD + p * 64;
            const float* al = s_align + p * 64;
            float sc = 0.f;
            #pragma unroll 4
            for (int j = 0; j < 64; ++j) sc = fmaf(crow[j], al[j], sc);
            s_part[t] = sc;
        }
        __syncthreads();
        if (t < CC) {
            float s = s_part[t] + s_part[64 + t] + s_part[128 + t] + s_part[192 + t];
            float m = s;
            for (int off = 32; off; off >>= 1) m = fmaxf(m, __shfl_xor(m, off, 64));
            float e = expf(s - m);
            float sum = e;
            for (int off = 32; off; off >>= 1) sum += __shfl_xor(sum, off, 64);
            s_att[t] = e / sum;
        }
        __syncthreads();
        {
            float ag = 0.f;
            #pragma unroll 4
            for (int c = 0; c < CC; ++c)
                ag = fmaf(s_att[c], CE[(size_t)s_rid[c] * DD + t], ag);
            if (side == 0) s_agg0[t] = ag; else s_agg1[t] = ag;
        }
        __syncthreads();
    }

    s_wl[t]  += s_wr[t];    // words_whole
    s_agg0[t] += s_agg1[t]; // cands_whole
    __syncthreads();

    float acc = b_c[t];
    #pragma unroll 4
    for (int k = 0; k < DD; ++k) acc = fmaf(s_wl[k],  W_c[k * DD + t], acc);
    #pragma unroll 4
    for (int k = 0; k < DD; ++k) acc = fmaf(s_agg0[k], W_c[(DD + k) * DD + t], acc);
    phrase[b * DD + t] = tanhf(acc);
}

// ---------------- Kernel 2: fp32 GEMM logits + per-chunk softmax partials ----------------
__global__ __launch_bounds__(256) void k_logits(
    const float* __restrict__ phrase, const float* __restrict__ CE,
    float* __restrict__ out, float* __restrict__ pmax, float* __restrict__ psum)
{
    const int bn = blockIdx.x, bm = blockIdx.y;
    const int n0 = bn * NT, m0 = bm * MT;
    const int t = threadIdx.x;
    const int ng = t & 31, mg = t >> 5;
    __shared__ float sp[KT][MT];   // phrase chunk [k][m]
    __shared__ float sc[KT][NT];   // CE chunk [k][n]
    float acc[8][4];
    #pragma unroll
    for (int i = 0; i < 8; ++i)
        #pragma unroll
        for (int j = 0; j < 4; ++j) acc[i][j] = 0.f;

    for (int k0 = 0; k0 < DD; k0 += KT) {
        __syncthreads();
        {   // stage phrase tile (64m x 16k) transposed
            const int m = t >> 2, kq = (t & 3) * 4;
            const float4 v = *(const float4*)(phrase + (m0 + m) * DD + k0 + kq);
            sp[kq + 0][m] = v.x; sp[kq + 1][m] = v.y;
            sp[kq + 2][m] = v.z; sp[kq + 3][m] = v.w;
        }
        #pragma unroll
        for (int i = 0; i < 2; ++i) {  // stage CE tile (128n x 16k) transposed
            const int idx = t + i * 256;
            const int n = idx >> 2, kq = (idx & 3) * 4;
            const int gn = n0 + n;
            float4 v = make_float4(0.f, 0.f, 0.f, 0.f);
            if (gn < VV) v = *(const float4*)(CE + (size_t)gn * DD + k0 + kq);
            sc[kq + 0][n] = v.x; sc[kq + 1][n] = v.y;
            sc[kq + 2][n] = v.z; sc[kq + 3][n] = v.w;
        }
        __syncthreads();
        #pragma unroll
        for (int k = 0; k < KT; ++k) {
            const float4 cv = *(const float4*)&sc[k][ng * 4];
            const float4 p0 = *(const float4*)&sp[k][mg * 8];
            const float4 p1 = *(const float4*)&sp[k][mg * 8 + 4];
            const float pm[8] = {p0.x, p0.y, p0.z, p0.w, p1.x, p1.y, p1.z, p1.w};
            const float cn[4] = {cv.x, cv.y, cv.z, cv.w};
            #pragma unroll
            for (int i = 0; i < 8; ++i)
                #pragma unroll
                for (int j = 0; j < 4; ++j)
                    acc[i][j] = fmaf(pm[i], cn[j], acc[i][j]);
        }
    }

    const int n = n0 + ng * 4;
    const bool nvalid = (n + 3) < VV;  // VV%4==0 -> all-or-none per float4
    #pragma unroll
    for (int i = 0; i < 8; ++i) {
        const int m = m0 + mg * 8 + i;
        if (nvalid) {
            *(float4*)(out + (size_t)m * VV + n) =
                make_float4(acc[i][0], acc[i][1], acc[i][2], acc[i][3]);
        }
        float lmax = -INFINITY;
        if (nvalid) lmax = fmaxf(fmaxf(acc[i][0], acc[i][1]), fmaxf(acc[i][2], acc[i][3]));
        #pragma unroll
        for (int off = 16; off; off >>= 1) lmax = fmaxf(lmax, __shfl_xor(lmax, off, 32));
        float lsum = 0.f;
        if (nvalid) {
            lsum = expf(acc[i][0] - lmax) + expf(acc[i][1] - lmax) +
                   expf(acc[i][2] - lmax) + expf(acc[i][3] - lmax);
        }
        #pragma unroll
        for (int off = 16; off; off >>= 1) lsum += __shfl_xor(lsum, off, 32);
        if (ng == 0) {
            pmax[(size_t)m * NCHUNK + bn] = lmax;
            psum[(size_t)m * NCHUNK + bn] = lsum;
        }
    }
}

// ---------------- Kernel 3: per-row online-softmax stat merge ----------------
__global__ __launch_bounds__(64) void k_rowstats(
    const float* __restrict__ pmax, const float* __restrict__ psum,
    float* __restrict__ rowM, float* __restrict__ rowS)
{
    const int b = blockIdx.x, t = threadIdx.x;
    float M = -INFINITY, S = 0.f;
    for (int c = t; c < NCHUNK; c += 64) {
        const float m = pmax[(size_t)b * NCHUNK + c];
        const float s = psum[(size_t)b * NCHUNK + c];
        const float nM = fmaxf(M, m);
        S = S * expf(M - nM) + s * expf(m - nM);
        M = nM;
    }
    #pragma unroll
    for (int off = 32; off; off >>= 1) {
        const float m2 = __shfl_xor(M, off, 64);
        const float s2 = __shfl_xor(S, off, 64);
        const float nM = fmaxf(M, m2);
        S = S * expf(M - nM) + s2 * expf(m2 - nM);
        M = nM;
    }
    if (t == 0) { rowM[b] = M; rowS[b] = S; }
}

// ---------------- Kernel 4: normalize in place + block top-k ----------------
__global__ __launch_bounds__(256) void k_norm_topk(
    float* __restrict__ ylogits, const float* __restrict__ rowM,
    const float* __restrict__ rowS, float* __restrict__ topk_out)
{
    const int b = blockIdx.x, t = threadIdx.x;
    const float M = rowM[b];
    const float invS = 1.f / rowS[b];
    float* row = ylogits + (size_t)b * VV;

    float tv[TOPK]; int ti[TOPK];
    #pragma unroll
    for (int j = 0; j < TOPK; ++j) { tv[j] = -1.f; ti[j] = 0x7fffffff; }

    for (int i0 = t * 4; i0 < VV; i0 += 1024) {
        const float4 v = *(const float4*)(row + i0);
        float4 y;
        y.x = expf(v.x - M) * invS;
        y.y = expf(v.y - M) * invS;
        y.z = expf(v.z - M) * invS;
        y.w = expf(v.w - M) * invS;
        *(float4*)(row + i0) = y;
        const float ya[4] = {y.x, y.y, y.z, y.w};
        #pragma unroll
        for (int j = 0; j < 4; ++j) {
            const float yv = ya[j]; const int yi = i0 + j;
            if (yv > tv[TOPK - 1] || (yv == tv[TOPK - 1] && yi < ti[TOPK - 1])) {
                float cv = yv; int ci = yi;
                #pragma unroll
                for (int p = 0; p < TOPK; ++p) {
                    const bool sw = (cv > tv[p]) || (cv == tv[p] && ci < ti[p]);
                    const float ov = tv[p]; const int oi = ti[p];
                    if (sw) { tv[p] = cv; ti[p] = ci; cv = ov; ci = oi; }
                }
            }
        }
    }

    __shared__ float sv[256 * TOPK];
    __shared__ int   si[256 * TOPK];
    #pragma unroll
    for (int j = 0; j < TOPK; ++j) { sv[t * TOPK + j] = tv[j]; si[t * TOPK + j] = ti[j]; }

    for (int span = 128; span >= 1; span >>= 1) {
        __syncthreads();
        if (t < span) {
            const int A = t * TOPK, B2 = (t + span) * TOPK;
            float rv[TOPK]; int ri[TOPK];
            int ia = 0, ib = 0;
            #pragma unroll
            for (int j = 0; j < TOPK; ++j) {
                const float av = sv[A + ia], bv = sv[B2 + ib];
                const int aidx = si[A + ia], bidx = si[B2 + ib];
                const bool takeA = (av > bv) || (av == bv && aidx < bidx);
                rv[j] = takeA ? av : bv;
                ri[j] = takeA ? aidx : bidx;
                if (takeA) ++ia; else ++ib;
            }
            #pragma unroll
            for (int j = 0; j < TOPK; ++j) { sv[A + j] = rv[j]; si[A + j] = ri[j]; }
        }
    }
    if (t == 0) {
        #pragma unroll
        for (int j = 0; j < TOPK; ++j) topk_out[b * TOPK + j] = (float)si[j];
    }
}

extern "C" void kernel_launch(void* const* d_in, const int* in_sizes, int n_in,
                              void* d_out, int out_size, void* d_ws, size_t ws_size,
                              hipStream_t stream) {
    const int*   wl_ids = (const int*)d_in[0];
    const int*   wr_ids = (const int*)d_in[1];
    const int*   cl_ids = (const int*)d_in[2];
    const int*   cr_ids = (const int*)d_in[3];
    const float* WE     = (const float*)d_in[4];
    const float* CE     = (const float*)d_in[5];
    const float* W_a    = (const float*)d_in[6];
    const float* b_a    = (const float*)d_in[7];
    const float* W_c    = (const float*)d_in[8];
    const float* b_c    = (const float*)d_in[9];

    float* out = (float*)d_out;
    float* ws  = (float*)d_ws;

    float* phrase = ws;                       // BB*DD           = 262144 floats
    float* pmax   = phrase + (size_t)BB * DD; // BB*NCHUNK       = 400384 floats
    float* psum   = pmax + (size_t)BB * NCHUNK;
    float* rowM   = psum + (size_t)BB * NCHUNK;
    float* rowS   = rowM + BB;
    float* topk_out = out + (size_t)BB * VV;

    k_phrase<<<BB, 256, 0, stream>>>(wl_ids, wr_ids, cl_ids, cr_ids,
                                     WE, CE, W_a, b_a, W_c, b_c, phrase);
    dim3 g(NCHUNK, BB / MT);
    k_logits<<<g, 256, 0, stream>>>(phrase, CE, out, pmax, psum);
    k_rowstats<<<BB, 64, 0, stream>>>(pmax, psum, rowM, rowS);
    k_norm_topk<<<BB, 256, 0, stream>>>(out, rowM, rowS, topk_out);
}

// Round 2
// 933.681 us; speedup vs baseline: 1.1337x; 1.1337x over previous
//
#include <hip/hip_runtime.h>
#include <math.h>

#define DD 256
#define BB 1024
#define CC 64
#define VV 50000
#define TOPK 10
#define BM 128
#define BN 128
#define BK 64
#define LDK 72          // padded LDS row stride (bf16 elems): 2-way bank alias = free
#define NCHUNK 391      // ceil(VV/BN)
#define MAXCAND 64

typedef __attribute__((ext_vector_type(8))) short bf16x8;
typedef __attribute__((ext_vector_type(4))) short bf16x4;
typedef __attribute__((ext_vector_type(4))) float f32x4;

__device__ inline unsigned short f2bf(float x) {
    unsigned u = __float_as_uint(x);
    unsigned r = (u + 0x7FFFu + ((u >> 16) & 1u)) >> 16;
    return (unsigned short)r;
}

__device__ inline bf16x8 load_bf8(const unsigned short* p) {
    // two 8-byte LDS loads (addresses are 8B-aligned; 16B would not be)
    bf16x4 lo = *(const bf16x4*)p;
    bf16x4 hi = *(const bf16x4*)(p + 4);
    bf16x8 r;
    r[0] = lo[0]; r[1] = lo[1]; r[2] = lo[2]; r[3] = lo[3];
    r[4] = hi[0]; r[5] = hi[1]; r[6] = hi[2]; r[7] = hi[3];
    return r;
}

// ---------------- Kernel 1: gather + attention + phrase (fp32 + bf16 copy) ----------------
__global__ __launch_bounds__(256) void k_phrase(
    const int* __restrict__ wl_ids, const int* __restrict__ wr_ids,
    const int* __restrict__ cl_ids, const int* __restrict__ cr_ids,
    const float* __restrict__ WE, const float* __restrict__ CE,
    const float* __restrict__ W_a, const float* __restrict__ b_a,
    const float* __restrict__ W_c, const float* __restrict__ b_c,
    float* __restrict__ phrase, unsigned short* __restrict__ phraseb)
{
    const int b = blockIdx.x;
    const int t = threadIdx.x;
    __shared__ float s_wl[DD], s_wr[DD], s_align[DD], s_agg0[DD], s_agg1[DD];
    __shared__ float s_part[256];
    __shared__ float s_att[CC];
    __shared__ int s_rid[CC];

    s_wl[t] = WE[(size_t)wl_ids[b] * DD + t];
    s_wr[t] = WE[(size_t)wr_ids[b] * DD + t];
    __syncthreads();

    for (int side = 0; side < 2; ++side) {
        const float* w    = (side == 0) ? s_wl : s_wr;
        const int*   cids = (side == 0) ? (cr_ids + b * CC) : (cl_ids + b * CC);

        float acc = b_a[t];
        #pragma unroll 4
        for (int k = 0; k < DD; ++k) acc = fmaf(w[k], W_a[k * DD + t], acc);
        s_align[t] = tanhf(acc);
        if (t < CC) s_rid[t] = cids[t];
        __syncthreads();

        {
            const int c = t & 63, p = t >> 6;
            const float* crow = CE + (size_t)s_rid[c] * DD + p * 64;
            const float* al = s_align + p * 64;
            float sc = 0.f;
            #pragma unroll 4
            for (int j = 0; j < 64; ++j) sc = fmaf(crow[j], al[j], sc);
            s_part[t] = sc;
        }
        __syncthreads();
        if (t < CC) {
            float s = s_part[t] + s_part[64 + t] + s_part[128 + t] + s_part[192 + t];
            float m = s;
            for (int off = 32; off; off >>= 1) m = fmaxf(m, __shfl_xor(m, off, 64));
            float e = expf(s - m);
            float sum = e;
            for (int off = 32; off; off >>= 1) sum += __shfl_xor(sum, off, 64);
            s_att[t] = e / sum;
        }
        __syncthreads();
        {
            float ag = 0.f;
            #pragma unroll 4
            for (int c = 0; c < CC; ++c)
                ag = fmaf(s_att[c], CE[(size_t)s_rid[c] * DD + t], ag);
            if (side == 0) s_agg0[t] = ag; else s_agg1[t] = ag;
        }
        __syncthreads();
    }

    s_wl[t]  += s_wr[t];
    s_agg0[t] += s_agg1[t];
    __syncthreads();

    float acc = b_c[t];
    #pragma unroll 4
    for (int k = 0; k < DD; ++k) acc = fmaf(s_wl[k],  W_c[k * DD + t], acc);
    #pragma unroll 4
    for (int k = 0; k < DD; ++k) acc = fmaf(s_agg0[k], W_c[(DD + k) * DD + t], acc);
    const float ph = tanhf(acc);
    phrase[b * DD + t] = ph;
    phraseb[b * DD + t] = f2bf(ph);
}

// ---------------- Kernel 2: bf16 MFMA GEMM logits + per-chunk softmax partials ----------------
__global__ __launch_bounds__(256) void k_logits_mfma(
    const unsigned short* __restrict__ phraseb, const float* __restrict__ CE,
    float* __restrict__ out, float* __restrict__ pmax, float* __restrict__ psum)
{
    __shared__ unsigned short sA[BM * LDK];
    __shared__ unsigned short sB[BN * LDK];
    __shared__ float sM[2][BM], sS[2][BM];

    const int t = threadIdx.x;
    const int wave = t >> 6, lane = t & 63;
    const int wm = wave >> 1, wn = wave & 1;
    const int quad = lane >> 4, l15 = lane & 15;
    const int n0 = blockIdx.x * BN, m0 = blockIdx.y * BM;

    f32x4 acc[4][4] = {};

    for (int k0 = 0; k0 < DD; k0 += BK) {
        __syncthreads();
        // stage A: phrase bf16 [128m][64k]
        #pragma unroll
        for (int r = 0; r < 4; ++r) {
            const int idx = t + r * 256;              // [0,1024)
            const int m = idx >> 3, k8 = (idx & 7) * 8;
            const uint4 v = *(const uint4*)(phraseb + (size_t)(m0 + m) * DD + k0 + k8);
            *(uint2*)(sA + m * LDK + k8)     = make_uint2(v.x, v.y);
            *(uint2*)(sA + m * LDK + k8 + 4) = make_uint2(v.z, v.w);
        }
        // stage B: CE fp32 [128n][64k] -> bf16 (cast in flight)
        #pragma unroll
        for (int r = 0; r < 8; ++r) {
            const int idx = t + r * 256;              // [0,2048)
            const int n = idx >> 4, k4 = (idx & 15) * 4;
            const int gn = n0 + n;
            float4 v = make_float4(0.f, 0.f, 0.f, 0.f);
            if (gn < VV) v = *(const float4*)(CE + (size_t)gn * DD + k0 + k4);
            ushort4 h;
            h.x = f2bf(v.x); h.y = f2bf(v.y); h.z = f2bf(v.z); h.w = f2bf(v.w);
            *(ushort4*)(sB + n * LDK + k4) = h;
        }
        __syncthreads();
        #pragma unroll
        for (int kk = 0; kk < BK; kk += 32) {
            bf16x8 af[4], bfr[4];
            #pragma unroll
            for (int i = 0; i < 4; ++i) {
                af[i]  = load_bf8(sA + (wm * 64 + i * 16 + l15) * LDK + kk + quad * 8);
                bfr[i] = load_bf8(sB + (wn * 64 + i * 16 + l15) * LDK + kk + quad * 8);
            }
            #pragma unroll
            for (int i = 0; i < 4; ++i)
                #pragma unroll
                for (int j = 0; j < 4; ++j)
                    acc[i][j] = __builtin_amdgcn_mfma_f32_16x16x32_bf16(af[i], bfr[j], acc[i][j], 0, 0, 0);
        }
    }

    // ---- store logits (fp32) ----
    bool val[4];
    #pragma unroll
    for (int j = 0; j < 4; ++j) val[j] = (n0 + wn * 64 + j * 16 + l15) < VV;

    #pragma unroll
    for (int i = 0; i < 4; ++i) {
        const int mbase = m0 + wm * 64 + i * 16 + quad * 4;
        #pragma unroll
        for (int r = 0; r < 4; ++r) {
            const int gm = mbase + r;
            #pragma unroll
            for (int j = 0; j < 4; ++j) {
                const int gn = n0 + wn * 64 + j * 16 + l15;
                if (val[j]) out[(size_t)gm * VV + gn] = acc[i][j][r];
            }
        }
    }

    // ---- per-row (128-col block) max & sumexp partials ----
    #pragma unroll
    for (int i = 0; i < 4; ++i) {
        #pragma unroll
        for (int r = 0; r < 4; ++r) {
            float mx = -INFINITY;
            #pragma unroll
            for (int j = 0; j < 4; ++j) if (val[j]) mx = fmaxf(mx, acc[i][j][r]);
            #pragma unroll
            for (int off = 8; off >= 1; off >>= 1) mx = fmaxf(mx, __shfl_xor(mx, off, 64));
            float s = 0.f;
            #pragma unroll
            for (int j = 0; j < 4; ++j) if (val[j]) s += expf(acc[i][j][r] - mx);
            #pragma unroll
            for (int off = 8; off >= 1; off >>= 1) s += __shfl_xor(s, off, 64);
            if (l15 == 0) {
                const int mloc = wm * 64 + i * 16 + quad * 4 + r;
                sM[wn][mloc] = mx;
                sS[wn][mloc] = s;
            }
        }
    }
    __syncthreads();
    if (t < BM) {
        const float Ma = sM[0][t], Mb = sM[1][t];
        const float nM = fmaxf(Ma, Mb);
        const float S = sS[0][t] * expf(Ma - nM) + sS[1][t] * expf(Mb - nM);
        pmax[(size_t)(m0 + t) * NCHUNK + blockIdx.x] = nM;
        psum[(size_t)(m0 + t) * NCHUNK + blockIdx.x] = S;
    }
}

// ---------------- Kernel 3: per-row online-softmax stat merge ----------------
__global__ __launch_bounds__(64) void k_rowstats(
    const float* __restrict__ pmax, const float* __restrict__ psum,
    float* __restrict__ rowM, float* __restrict__ rowS)
{
    const int b = blockIdx.x, t = threadIdx.x;
    float M = -INFINITY, S = 0.f;
    for (int c = t; c < NCHUNK; c += 64) {
        const float m = pmax[(size_t)b * NCHUNK + c];
        const float s = psum[(size_t)b * NCHUNK + c];
        const float nM = fmaxf(M, m);
        S = S * expf(M - nM) + s * expf(m - nM);
        M = nM;
    }
    #pragma unroll
    for (int off = 32; off; off >>= 1) {
        const float m2 = __shfl_xor(M, off, 64);
        const float s2 = __shfl_xor(S, off, 64);
        const float nM = fmaxf(M, m2);
        S = S * expf(M - nM) + s2 * expf(m2 - nM);
        M = nM;
    }
    if (t == 0) { rowM[b] = M; rowS[b] = S; }
}

// ---------------- Kernel 4: normalize in place + approx top-10 + candidate emit ----------------
__global__ __launch_bounds__(256) void k_norm_topk(
    float* __restrict__ ylogits, const float* __restrict__ rowM,
    const float* __restrict__ rowS, int* __restrict__ cand_idx,
    int* __restrict__ cand_cnt)
{
    const int b = blockIdx.x, t = threadIdx.x;
    const float M = rowM[b];
    const float invS = 1.f / rowS[b];
    float* row = ylogits + (size_t)b * VV;

    float tv[TOPK]; int ti[TOPK];
    #pragma unroll
    for (int j = 0; j < TOPK; ++j) { tv[j] = -1.f; ti[j] = 0x7fffffff; }

    for (int i0 = t * 4; i0 < VV; i0 += 1024) {
        const float4 v = *(const float4*)(row + i0);
        float4 y;
        y.x = expf(v.x - M) * invS;
        y.y = expf(v.y - M) * invS;
        y.z = expf(v.z - M) * invS;
        y.w = expf(v.w - M) * invS;
        *(float4*)(row + i0) = y;
        const float ya[4] = {y.x, y.y, y.z, y.w};
        #pragma unroll
        for (int j = 0; j < 4; ++j) {
            const float yv = ya[j]; const int yi = i0 + j;
            if (yv > tv[TOPK - 1] || (yv == tv[TOPK - 1] && yi < ti[TOPK - 1])) {
                float cv = yv; int ci = yi;
                #pragma unroll
                for (int p = 0; p < TOPK; ++p) {
                    const bool sw = (cv > tv[p]) || (cv == tv[p] && ci < ti[p]);
                    const float ov = tv[p]; const int oi = ti[p];
                    if (sw) { tv[p] = cv; ti[p] = ci; cv = ov; ci = oi; }
                }
            }
        }
    }

    __shared__ float sv[256 * TOPK];
    __shared__ int   si[256 * TOPK];
    #pragma unroll
    for (int j = 0; j < TOPK; ++j) { sv[t * TOPK + j] = tv[j]; si[t * TOPK + j] = ti[j]; }

    for (int span = 128; span >= 1; span >>= 1) {
        __syncthreads();
        if (t < span) {
            const int A = t * TOPK, B2 = (t + span) * TOPK;
            float rv[TOPK]; int ri[TOPK];
            int ia = 0, ib = 0;
            #pragma unroll
            for (int j = 0; j < TOPK; ++j) {
                const float av = sv[A + ia], bv = sv[B2 + ib];
                const int aidx = si[A + ia], bidx = si[B2 + ib];
                const bool takeA = (av > bv) || (av == bv && aidx < bidx);
                rv[j] = takeA ? av : bv;
                ri[j] = takeA ? aidx : bidx;
                if (takeA) ++ia; else ++ib;
            }
            #pragma unroll
            for (int j = 0; j < TOPK; ++j) { sv[A + j] = rv[j]; si[A + j] = ri[j]; }
        }
    }

    // ---- candidate emission: everything within 10% of the 10th approx prob ----
    __shared__ float s_th;
    __shared__ int s_cnt;
    __shared__ int s_cidx[MAXCAND];
    if (t == 0) { s_th = sv[9] * 0.90f; s_cnt = 0; }
    __syncthreads();
    const float th = s_th;
    for (int i0 = t * 4; i0 < VV; i0 += 1024) {
        const float4 y = *(const float4*)(row + i0);
        const float ya[4] = {y.x, y.y, y.z, y.w};
        #pragma unroll
        for (int j = 0; j < 4; ++j) {
            if (ya[j] >= th) {
                const int p = atomicAdd(&s_cnt, 1);
                if (p < MAXCAND) s_cidx[p] = i0 + j;
            }
        }
    }
    __syncthreads();
    if (t == 0) cand_cnt[b] = (s_cnt < MAXCAND) ? s_cnt : MAXCAND;
    if (t < MAXCAND && t < s_cnt) cand_idx[b * MAXCAND + t] = s_cidx[t];
}

// ---------------- Kernel 5: exact fp32 rescore of candidates -> final indices ----------------
__global__ __launch_bounds__(64) void k_rescore(
    const float* __restrict__ phrase, const float* __restrict__ CE,
    const int* __restrict__ cand_idx, const int* __restrict__ cand_cnt,
    float* __restrict__ topk_out)
{
    const int b = blockIdx.x, lane = threadIdx.x;
    int cnt = cand_cnt[b];
    if (cnt > MAXCAND) cnt = MAXCAND;
    __shared__ float s_val[MAXCAND];
    __shared__ int   s_idx[MAXCAND];

    const float4 ph = *(const float4*)(phrase + (size_t)b * DD + lane * 4);
    for (int c = 0; c < cnt; ++c) {
        const int id = cand_idx[b * MAXCAND + c];
        const float4 ce = *(const float4*)(CE + (size_t)id * DD + lane * 4);
        float d = ph.x * ce.x + ph.y * ce.y + ph.z * ce.z + ph.w * ce.w;
        #pragma unroll
        for (int off = 32; off; off >>= 1) d += __shfl_xor(d, off, 64);
        if (lane == 0) { s_val[c] = d; s_idx[c] = id; }
    }
    __syncthreads();
    if (lane == 0) {
        for (int j = 0; j < TOPK; ++j) {
            int best = j;
            for (int c = j + 1; c < cnt; ++c) {
                if (s_val[c] > s_val[best] ||
                    (s_val[c] == s_val[best] && s_idx[c] < s_idx[best])) best = c;
            }
            const float bv = s_val[best]; const int bi = s_idx[best];
            s_val[best] = s_val[j]; s_idx[best] = s_idx[j];
            s_val[j] = bv; s_idx[j] = bi;
            topk_out[b * TOPK + j] = (float)bi;
        }
    }
}

extern "C" void kernel_launch(void* const* d_in, const int* in_sizes, int n_in,
                              void* d_out, int out_size, void* d_ws, size_t ws_size,
                              hipStream_t stream) {
    const int*   wl_ids = (const int*)d_in[0];
    const int*   wr_ids = (const int*)d_in[1];
    const int*   cl_ids = (const int*)d_in[2];
    const int*   cr_ids = (const int*)d_in[3];
    const float* WE     = (const float*)d_in[4];
    const float* CE     = (const float*)d_in[5];
    const float* W_a    = (const float*)d_in[6];
    const float* b_a    = (const float*)d_in[7];
    const float* W_c    = (const float*)d_in[8];
    const float* b_c    = (const float*)d_in[9];

    float* out = (float*)d_out;
    float* ws  = (float*)d_ws;

    float* phrase = ws;                                         // 262144 f
    unsigned short* phraseb = (unsigned short*)(ws + 262144);   // 262144 bf16 = 131072 f
    float* pmax   = ws + 262144 + 131072;                       // 400384 f
    float* psum   = pmax + (size_t)BB * NCHUNK;                 // 400384 f
    float* rowM   = psum + (size_t)BB * NCHUNK;                 // 1024 f
    float* rowS   = rowM + BB;                                  // 1024 f
    int*   cand_idx = (int*)(rowS + BB);                        // 65536 i
    int*   cand_cnt = cand_idx + (size_t)BB * MAXCAND;          // 1024 i
    float* topk_out = out + (size_t)BB * VV;

    k_phrase<<<BB, 256, 0, stream>>>(wl_ids, wr_ids, cl_ids, cr_ids,
                                     WE, CE, W_a, b_a, W_c, b_c, phrase, phraseb);
    dim3 g(NCHUNK, BB / BM);
    k_logits_mfma<<<g, 256, 0, stream>>>(phraseb, CE, out, pmax, psum);
    k_rowstats<<<BB, 64, 0, stream>>>(pmax, psum, rowM, rowS);
    k_norm_topk<<<BB, 256, 0, stream>>>(out, rowM, rowS, cand_idx, cand_cnt);
    k_rescore<<<BB, 64, 0, stream>>>(phrase, CE, cand_idx, cand_cnt, topk_out);
}